// Round 6
// baseline (183.569 us; speedup 1.0000x reference)
//
#include <hip/hip_runtime.h>
#include <hip/hip_bf16.h>

typedef __hip_bfloat16 bf16;
typedef __attribute__((ext_vector_type(8))) short bf16x8;
typedef __attribute__((ext_vector_type(4))) float floatx4;

#define NB 16
#define NC 256
#define NPIX 4096
#define NHID 128
#define NH 4
#define ND 32
#define NMEM 4
#define QSCALE 0.17677669529663687f  // 32^-0.5

#define LGKM0()  asm volatile("s_waitcnt lgkmcnt(0)" ::: "memory")

// ---------------- kW: pack wqkv*g -> bf16 in MFMA A-frag tile order.
// Also zeroes zacc (ctx is now slab-privatized -> no zeroing needed).
__launch_bounds__(256)
__global__ void kW(const float* __restrict__ wqkv, const float* __restrict__ g,
                   bf16* __restrict__ wgpack, float* __restrict__ zacc){
  const int u = blockIdx.x*256 + threadIdx.x;     // 12288 chunks
  if (u < NB*NHID) zacc[u] = 0.f;
  const int s = u / 1536;
  const int r = u - s*1536;
  const int tile = r >> 6, l = r & 63;
  const int row = tile*16 + (l & 15);
  const int kb  = s*32 + (l >> 4)*8;
  const float* wp = wqkv + (size_t)row*NC + kb;
  floatx4 w0 = *(const floatx4*)wp;
  floatx4 w1 = *(const floatx4*)(wp + 4);
  floatx4 g0 = *(const floatx4*)(g + kb);
  floatx4 g1 = *(const floatx4*)(g + kb + 4);
  alignas(16) bf16 tmp[8];
  #pragma unroll
  for (int i = 0; i < 4; ++i){
    tmp[i]   = __float2bfloat16(w0[i]*g0[i]);
    tmp[4+i] = __float2bfloat16(w1[i]*g1[i]);
  }
  *(uint4*)(wgpack + (size_t)u*8) = *(const uint4*)tmp;
}

// ---------------- kA v6: PX=128 per block (2 x 64-px subtiles), grid 32x16.
// ctx partials accumulate in REGISTERS across subtiles, then one dense slab
// store per block -> ZERO ctx atomics (was 4.2M device-scope atomics).
// GEMM datapath = v5 (reg-direct weights, Xb dbuf, lgkm-only barriers).
__launch_bounds__(256)
__global__ void kA(const float* __restrict__ x, const bf16* __restrict__ wgpack,
                   float* __restrict__ dout,
                   float* __restrict__ ctxp, float* __restrict__ zacc){
  __shared__ char smem alignas(16) [48384];
  bf16 (*Pb)[72] = (bf16(*)[72])smem;            // [128][72] = 18432 (post)
  bf16 (*Vb)[72] = (bf16(*)[72])(smem + 18432);  // [128][72] = 18432 (post) -> 36864
  // Xb[buf][64][40] bf16 @ 36864 + buf*5120 (GEMM)
  float* ssqL = (float*)(smem + 47104);          // [4][64]
  float* sL   = (float*)(smem + 48128);          // [64]
  const int t = threadIdx.x;
  const int pxg = blockIdx.x, b = blockIdx.y;    // pxg: 0..31
  const int wv = t >> 6, lane = t & 63, m = lane & 15, q4 = lane >> 4;
  const int px_st = t & 63, cg_st = t >> 6;
  const float* xb = x + (size_t)b*NC*NPIX;
  float xr[2][8];
  bf16x8 af[2][6];
  floatx4 cx[2][2] = {};                         // ctx accum across both subtiles

  for (int sub = 0; sub < 2; ++sub){
    const int pb = pxg*128 + sub*64;
    float ssq = 0.f;

    auto xissue = [&](int c, float* dst){   // 8 scalar global loads, no use yet
      const float* xp = xb + (size_t)(c*32 + cg_st*8)*NPIX + pb + px_st;
      #pragma unroll
      for (int j = 0; j < 8; ++j) dst[j] = xp[(size_t)j*NPIX];
    };
    auto xwrite = [&](int c, const float* v){  // cvt + ssq + ds_write into Xb[c&1]
      alignas(16) bf16 tmp[8];
      #pragma unroll
      for (int j = 0; j < 8; ++j){
        ssq += v[j]*v[j];
        tmp[j] = __float2bfloat16(v[j]);
      }
      bf16 (*Xb)[40] = (bf16(*)[40])(smem + 36864 + (c&1)*5120);
      *(uint4*)&Xb[px_st][cg_st*8] = *(const uint4*)tmp;
    };
    auto wload = [&](int c, int rt)->bf16x8 {  // wave-private frag, lane-identity
      return *(const bf16x8*)(wgpack + ((size_t)(c*24 + wv*6 + rt)*64 + lane)*8);
    };

    // prologue
    xissue(0, xr[0]);
    #pragma unroll
    for (int rt = 0; rt < 6; ++rt) af[0][rt] = wload(0, rt);
    xissue(1, xr[1]);
    xwrite(0, xr[0]);          // compiler waits the x(0) regs
    LGKM0();
    __builtin_amdgcn_s_barrier();

    floatx4 acc[6][4] = {};
    #pragma unroll
    for (int s = 0; s < 8; ++s){
      const int buf = s & 1;
      bf16 (*Xb)[40] = (bf16(*)[40])(smem + 36864 + buf*5120);
      bf16x8 bfr[4];
      #pragma unroll
      for (int pt = 0; pt < 4; ++pt)
        bfr[pt] = *(const bf16x8*)&Xb[pt*16 + m][q4*8];
      if (s < 7){  // weight frags for s+1: plain loads, ride across the barrier
        #pragma unroll
        for (int rt = 0; rt < 6; ++rt) af[(s+1)&1][rt] = wload(s + 1, rt);
      }
      if (s < 6) xissue(s + 2, xr[buf]);
      #pragma unroll
      for (int rt = 0; rt < 6; ++rt)
        #pragma unroll
        for (int pt = 0; pt < 4; ++pt)
          acc[rt][pt] = __builtin_amdgcn_mfma_f32_16x16x32_bf16(af[buf][rt], bfr[pt], acc[rt][pt], 0, 0, 0);
      if (s < 7) xwrite(s + 1, xr[buf ^ 1]);
      LGKM0();                 // Xb writes visible; no vmcnt wait in the loop
      __builtin_amdgcn_s_barrier();
    }
    // finalize s (per px)
    ssqL[cg_st*64 + px_st] = ssq;
    __syncthreads();
    if (t < 64){
      float tot = ssqL[t] + ssqL[64 + t] + ssqL[128 + t] + ssqL[192 + t];
      sL[t] = 16.0f / fmaxf(sqrtf(tot), 1e-12f);
    }
    __syncthreads();   // sL ready; GEMM Xb reads done -> Pb/Vb writable
    float sv[4];
    #pragma unroll
    for (int pt = 0; pt < 4; ++pt) sv[pt] = sL[pt*16 + m];
    #pragma unroll
    for (int pr = 0; pr < 3; ++pr){
      const int ra = 2*pr, rb = 2*pr + 1;
      const int row0 = wv*96 + pr*32;
      const int type = row0 >> 7;          // 0=q, 1=k, 2=v
      if (type == 0){
        const int slice = row0 >> 5;       // head = q k-slice
        const int j0 = (q4 & 1)*4;
        #pragma unroll
        for (int pt = 0; pt < 4; ++pt){
          float va[4], vb[4];
          float mx = -1e30f;
          #pragma unroll
          for (int r = 0; r < 4; ++r){
            va[r] = acc[ra][pt][r]*sv[pt];
            vb[r] = acc[rb][pt][r]*sv[pt];
            mx = fmaxf(mx, fmaxf(va[r], vb[r]));
          }
          mx = fmaxf(mx, __shfl_xor(mx, 16, 64));
          mx = fmaxf(mx, __shfl_xor(mx, 32, 64));
          float se = 0.f;
          #pragma unroll
          for (int r = 0; r < 4; ++r){
            va[r] = __expf(va[r] - mx); vb[r] = __expf(vb[r] - mx);
            se += va[r] + vb[r];
          }
          se += __shfl_xor(se, 16, 64);
          se += __shfl_xor(se, 32, 64);
          const float inv = QSCALE / se;
          alignas(8) bf16 pka[4], pkb[4];
          #pragma unroll
          for (int r = 0; r < 4; ++r){
            pka[r] = __float2bfloat16(va[r]*inv);
            pkb[r] = __float2bfloat16(vb[r]*inv);
          }
          const int ca = (slice*4 + pt)*4 + (q4 >> 1);
          const int cb = ca + 2;
          bf16* pa = (bf16*)(dout + (size_t)(b*NC + ca)*NPIX + pb) + m*8 + j0;
          bf16* pv = (bf16*)(dout + (size_t)(b*NC + cb)*NPIX + pb) + m*8 + j0;
          *(uint2*)pa = *(const uint2*)pka;
          *(uint2*)pv = *(const uint2*)pkb;
        }
      } else if (type == 1){
        const int d0 = row0 - 128;
        float za[4] = {}, zb[4] = {};
        #pragma unroll
        for (int pt = 0; pt < 4; ++pt){
          #pragma unroll
          for (int r = 0; r < 4; ++r){
            float pa = __expf(acc[ra][pt][r]*sv[pt]);
            float pv = __expf(acc[rb][pt][r]*sv[pt]);
            za[r] += pa; zb[r] += pv;
            Pb[d0      + q4*4 + r][pt*16 + m] = __float2bfloat16(pa);
            Pb[d0 + 16 + q4*4 + r][pt*16 + m] = __float2bfloat16(pv);
          }
        }
        #pragma unroll
        for (int r = 0; r < 4; ++r){
          #pragma unroll
          for (int o = 1; o < 16; o <<= 1){
            za[r] += __shfl_xor(za[r], o, 64);
            zb[r] += __shfl_xor(zb[r], o, 64);
          }
        }
        if (m == 0){
          #pragma unroll
          for (int r = 0; r < 4; ++r){
            atomicAdd(&zacc[b*NHID + d0      + q4*4 + r], za[r]);
            atomicAdd(&zacc[b*NHID + d0 + 16 + q4*4 + r], zb[r]);
          }
        }
      } else {
        const int v0 = row0 - 256;
        #pragma unroll
        for (int pt = 0; pt < 4; ++pt)
          #pragma unroll
          for (int r = 0; r < 4; ++r){
            Vb[v0      + q4*4 + r][pt*16 + m] = __float2bfloat16(acc[ra][pt][r]*sv[pt]);
            Vb[v0 + 16 + q4*4 + r][pt*16 + m] = __float2bfloat16(acc[rb][pt][r]*sv[pt]);
          }
      }
    }
    __syncthreads();
    // ctx MFMA: wave wv = head wv; 64 toks in 2 K-steps; cx accumulates across subs
    #pragma unroll
    for (int k0t = 0; k0t < 64; k0t += 32){
      bf16x8 af2[2], bf2[2];
      #pragma unroll
      for (int dt = 0; dt < 2; ++dt) af2[dt] = *(const bf16x8*)&Pb[wv*32 + dt*16 + m][k0t + q4*8];
      #pragma unroll
      for (int et = 0; et < 2; ++et) bf2[et] = *(const bf16x8*)&Vb[wv*32 + et*16 + m][k0t + q4*8];
      #pragma unroll
      for (int dt = 0; dt < 2; ++dt)
        #pragma unroll
        for (int et = 0; et < 2; ++et)
          cx[dt][et] = __builtin_amdgcn_mfma_f32_16x16x32_bf16(af2[dt], bf2[et], cx[dt][et], 0, 0, 0);
    }
    // next sub's prologue barrier (lgkm drain) orders these Pb/Vb reads
    // before sub1's post-phase rewrites.
  }
  // dense slab store (replaces 4096 atomics/block)
  float* cb2 = ctxp + (size_t)(b*32 + pxg)*4096 + wv*1024;
  #pragma unroll
  for (int dt = 0; dt < 2; ++dt)
    #pragma unroll
    for (int et = 0; et < 2; ++et)
      #pragma unroll
      for (int r = 0; r < 4; ++r)
        cb2[(dt*16 + q4*4 + r)*32 + et*16 + m] = cx[dt][et][r];
}

// ---------------- k4 v3: cooperative slab reduction (32 slabs/b) -> ctxL,
// then in-place ctx'' transform, then the Weff GEMM (unchanged).
__launch_bounds__(256)
__global__ void k4_weff(const float* __restrict__ ctxp, const float* __restrict__ zacc,
                        const float* __restrict__ memkv, const float* __restrict__ wout,
                        bf16* __restrict__ wpack){
  __shared__ float ctxL[4][32][32];        // 16384 B (flat: h*1024 + d*32 + e)
  __shared__ float woutL[64][129];         // 33024 B
  const int t = threadIdx.x;
  const int o0 = blockIdx.x * 64, b = blockIdx.y;
  {  // stage wout[o0..o0+64][0..128], coalesced
    const float* ws = wout + (size_t)o0*NHID;
    #pragma unroll
    for (int i = 0; i < 32; ++i){
      const int idx = i*256 + t;
      woutL[idx >> 7][idx & 127] = ws[idx];
    }
  }
  {  // reduce 32 slabs -> raw ctx sums in ctxL (thread t owns float4 i*1024 + t*4)
    floatx4 s4[4] = {};
    for (int sb = 0; sb < 32; ++sb){
      const float* slab = ctxp + (size_t)(b*32 + sb)*4096;
      #pragma unroll
      for (int i = 0; i < 4; ++i)
        s4[i] += *(const floatx4*)(slab + i*1024 + t*4);
    }
    #pragma unroll
    for (int i = 0; i < 4; ++i)
      *(floatx4*)((float*)ctxL + i*1024 + t*4) = s4[i];
  }
  __syncthreads();
  if (t < 128){  // hd = t: fold mem-kv + invz into ctx'' (in-place, own row)
    const int h = t >> 5, d = t & 31;
    const float* mk = memkv + t*NMEM;
    float me[4]; float z = zacc[b*NHID + t];
    #pragma unroll
    for (int j = 0; j < 4; ++j){ me[j] = __expf(mk[j]); z += me[j]; }
    const float invz = 1.0f / z;
    float* cp = (float*)ctxL + h*1024 + d*32;
    const float* mv = memkv + (size_t)(NHID + h*ND)*NMEM;
    #pragma unroll
    for (int e = 0; e < ND; ++e){
      float ce = cp[e];
      #pragma unroll
      for (int j = 0; j < 4; ++j) ce += me[j]*mv[e*NMEM + j];
      cp[e] = ce * invz;
    }
  }
  __syncthreads();
  const int ol = t & 63, g = t >> 6;
  float out[32] = {};
  #pragma unroll
  for (int e = 0; e < 32; ++e){
    const float we = woutL[ol][g*32 + e];
    #pragma unroll
    for (int d = 0; d < 32; ++d) out[d] += ctxL[g][d][e] * we;
  }
  const int o = o0 + ol, tile = o >> 4, m16 = o & 15;
  #pragma unroll
  for (int q4k = 0; q4k < 4; ++q4k){
    alignas(16) bf16 tmp[8];
    #pragma unroll
    for (int j = 0; j < 8; ++j) tmp[j] = __float2bfloat16(out[q4k*8 + j]);
    *(uint4*)(wpack + ((size_t)((b*4 + g)*16 + tile)*64 + q4k*16 + m16)*8) = *(const uint4*)tmp;
  }
}

// ---------------- K5 v5: fully register-direct (unchanged).
__launch_bounds__(256)
__global__ void k5_out(float* dout, const bf16* __restrict__ wpack,
                       const float* __restrict__ bout, const float* __restrict__ gout){
  __shared__ float red[256];
  __shared__ float nf[64];
  const int t = threadIdx.x;
  const int pb = blockIdx.x * 64, b = blockIdx.y;
  const int wv = t >> 6, lane = t & 63, m = lane & 15, q4 = lane >> 4;
  bf16x8 wf[4][4], qf[4][4];
  #pragma unroll
  for (int s = 0; s < 4; ++s){
    #pragma unroll
    for (int rt = 0; rt < 4; ++rt)
      wf[s][rt] = *(const bf16x8*)(wpack + ((size_t)((b*4 + s)*16 + wv*4 + rt)*64 + lane)*8);
    #pragma unroll
    for (int pt = 0; pt < 4; ++pt)
      qf[s][pt] = *(const bf16x8*)((const char*)(dout + (size_t)(b*NC + (s*4 + pt)*4 + q4)*NPIX + pb) + m*16);
  }
  floatx4 acc[4][4] = {};
  #pragma unroll
  for (int s = 0; s < 4; ++s)
    #pragma unroll
    for (int rt = 0; rt < 4; ++rt)
      #pragma unroll
      for (int pt = 0; pt < 4; ++pt)
        acc[rt][pt] = __builtin_amdgcn_mfma_f32_16x16x32_bf16(wf[s][rt], qf[s][pt], acc[rt][pt], 0, 0, 0);
  // bias + ssq partials
  float ps[4] = {0.f, 0.f, 0.f, 0.f};
  #pragma unroll
  for (int rt = 0; rt < 4; ++rt){
    const int row = wv*64 + rt*16 + q4*4;
    #pragma unroll
    for (int r = 0; r < 4; ++r){
      const float bias = bout[row + r];
      #pragma unroll
      for (int pt = 0; pt < 4; ++pt){
        acc[rt][pt][r] += bias;
        ps[pt] += acc[rt][pt][r]*acc[rt][pt][r];
      }
    }
  }
  #pragma unroll
  for (int pt = 0; pt < 4; ++pt){
    ps[pt] += __shfl_xor(ps[pt], 16, 64);
    ps[pt] += __shfl_xor(ps[pt], 32, 64);
  }
  if (q4 == 0){
    #pragma unroll
    for (int pt = 0; pt < 4; ++pt) red[wv*64 + pt*16 + m] = ps[pt];
  }
  __syncthreads();
  if (t < 64){
    float tot = red[t] + red[64 + t] + red[128 + t] + red[192 + t];
    nf[t] = 16.0f / fmaxf(sqrtf(tot), 1e-12f);
  }
  __syncthreads();
  float nv[4];
  #pragma unroll
  for (int pt = 0; pt < 4; ++pt) nv[pt] = nf[pt*16 + m];
  #pragma unroll
  for (int rt = 0; rt < 4; ++rt){
    const int row = wv*64 + rt*16 + q4*4;
    #pragma unroll
    for (int r = 0; r < 4; ++r){
      const float gg = gout[row + r];
      float* op = dout + (size_t)(b*NC + row + r)*NPIX + pb + m;
      #pragma unroll
      for (int pt = 0; pt < 4; ++pt)
        op[pt*16] = acc[rt][pt][r]*nv[pt]*gg;
    }
  }
}

extern "C" void kernel_launch(void* const* d_in, const int* in_sizes, int n_in,
                              void* d_out, int out_size, void* d_ws, size_t ws_size,
                              hipStream_t stream) {
  (void)in_sizes; (void)n_in; (void)out_size; (void)ws_size;
  const float* x     = (const float*)d_in[0];
  const float* ng    = (const float*)d_in[1];
  const float* wqkv  = (const float*)d_in[2];
  const float* memkv = (const float*)d_in[3];
  const float* wout  = (const float*)d_in[4];
  const float* bout  = (const float*)d_in[5];
  const float* gout  = (const float*)d_in[6];
  float* dout = (float*)d_out;
  char* ws = (char*)d_ws;
  // workspace layout — total ~9.7 MB
  bf16*  wgpack = (bf16*)(ws);              // 196,608
  bf16*  wpack  = (bf16*)(ws + 196608);     // 1,048,576 -> ends 1,245,184
  float* zacc   = (float*)(ws + 1245184);   // 16*128*4 = 8,192
  float* ctxp   = (float*)(ws + 1310720);   // 512 slabs * 16KB = 8,388,608 -> ends 9,699,328

  kW     <<<dim3(48),      256, 0, stream>>>(wqkv, ng, wgpack, zacc);
  kA     <<<dim3(32, 16),  256, 0, stream>>>(x, wgpack, dout, ctxp, zacc);
  k4_weff<<<dim3(4, 16),   256, 0, stream>>>(ctxp, zacc, memkv, wout, wpack);
  k5_out <<<dim3(64, 16),  256, 0, stream>>>(dout, wpack, bout, gout);
}